// Round 1
// 673.821 us; speedup vs baseline: 1.0478x; 1.0478x over previous
//
#include <hip/hip_runtime.h>
#include <stdint.h>

#define N_U 20000
#define N_V 20000
#define N_E 320000
#define EPS_F 1e-5f
#define NEG_HUGE -3.402823466e38f

using bf16x8 = __attribute__((__ext_vector_type__(8))) __bf16;
using f32x4  = __attribute__((__ext_vector_type__(4))) float;

__device__ __forceinline__ unsigned short f2bf(float f) {
  unsigned int u = __float_as_uint(f);
  u += 0x7FFFu + ((u >> 16) & 1u);
  return (unsigned short)(u >> 16);
}

__device__ __forceinline__ float b2f(unsigned short u) {
  return __uint_as_float((unsigned int)u << 16);
}

__device__ __forceinline__ ushort4 bf4(float4 v) {
  return make_ushort4(f2bf(v.x), f2bf(v.y), f2bf(v.z), f2bf(v.w));
}

// ---- logits for both node sets: one wave per node ----
__global__ void k_logits2(const float* __restrict__ xus, const float* __restrict__ xvs,
                          const float* __restrict__ attn_u2v, const float* __restrict__ attn_v2u,
                          float* __restrict__ logits_u, float* __restrict__ logits_v) {
  int wid = (blockIdx.x * 256 + threadIdx.x) >> 6;
  int lane = threadIdx.x & 63;
  bool isU = wid < N_U;
  int node = isU ? wid : wid - N_U;
  const float4* x4 = reinterpret_cast<const float4*>(isU ? xus : xvs);
  const float4* a4 = reinterpret_cast<const float4*>(isU ? attn_u2v : attn_v2u);
  float4 xv = x4[(size_t)node * 64 + lane];
  float4 av = a4[lane];
  float s = xv.x * av.x + xv.y * av.y + xv.z * av.z + xv.w * av.w;
#pragma unroll
  for (int o = 32; o; o >>= 1) s += __shfl_down(s, o);
  if (lane == 0) (isU ? logits_u : logits_v)[node] = s;
}

// ---- global softmax stats (max, sumexp) — block 0: logits_u -> stat[0..1], block 1: logits_v -> stat[4..5]
__global__ void k_softmax_stat(const float* __restrict__ lu, const float* __restrict__ lv,
                               float* __restrict__ stat, int n) {
  const float* l = blockIdx.x ? lv : lu;
  float* st = stat + (blockIdx.x ? 4 : 0);
  __shared__ float red[16];
  __shared__ float sm;
  int t = threadIdx.x;
  float m = NEG_HUGE;
  for (int i = t; i < n; i += 1024) m = fmaxf(m, l[i]);
#pragma unroll
  for (int o = 32; o; o >>= 1) m = fmaxf(m, __shfl_down(m, o));
  if ((t & 63) == 0) red[t >> 6] = m;
  __syncthreads();
  if (t == 0) {
    float mm = red[0];
    for (int i = 1; i < 16; i++) mm = fmaxf(mm, red[i]);
    sm = mm;
  }
  __syncthreads();
  float mx = sm;
  float s = 0.f;
  for (int i = t; i < n; i += 1024) s += __expf(l[i] - mx);
#pragma unroll
  for (int o = 32; o; o >>= 1) s += __shfl_down(s, o);
  __syncthreads();
  if ((t & 63) == 0) red[t >> 6] = s;
  __syncthreads();
  if (t == 0) {
    float ss = 0.f;
    for (int i = 0; i < 16; i++) ss += red[i];
    st[0] = mx;
    st[1] = ss;
  }
}

// ---- pre-weight sources with attention (bf16) + write self-features into h ----
// One wave per node, both sides. xw_u = a_u * xus (bf16), xw_v = a_v * xvs (bf16).
// h self part (cols 0..255) = bf16(xt row).
__global__ void k_preweight(const float* __restrict__ xus, const float* __restrict__ xvs,
                            const float* __restrict__ xut, const float* __restrict__ xvt,
                            const float* __restrict__ logits_u, const float* __restrict__ logits_v,
                            const float* __restrict__ smstat,
                            unsigned short* __restrict__ xw_u, unsigned short* __restrict__ xw_v,
                            unsigned short* __restrict__ h_u, unsigned short* __restrict__ h_v) {
  int wid = (blockIdx.x * 256 + threadIdx.x) >> 6;
  int lane = threadIdx.x & 63;
  bool isU = wid < N_U;
  int node = isU ? wid : wid - N_U;
  const float4* xs4 = reinterpret_cast<const float4*>(isU ? xus : xvs);
  const float4* xt4 = reinterpret_cast<const float4*>(isU ? xut : xvt);
  const float* lg = isU ? logits_u : logits_v;
  float mx = smstat[isU ? 0 : 4];
  float ise = 1.f / smstat[isU ? 1 : 5];
  unsigned short* xw = isU ? xw_u : xw_v;
  unsigned short* h = isU ? h_u : h_v;

  float a = __expf(lg[node] - mx) * ise;
  float4 xv = xs4[(size_t)node * 64 + lane];
  ushort4* xw4 = reinterpret_cast<ushort4*>(xw + (size_t)node * 256);
  xw4[lane] = bf4(make_float4(a * xv.x, a * xv.y, a * xv.z, a * xv.w));
  float4 tv = xt4[(size_t)node * 64 + lane];
  ushort4* h4 = reinterpret_cast<ushort4*>(h + (size_t)node * 896);
  h4[lane] = bf4(tv);
}

// ---- CSR build, both graphs in one launch ----
__global__ void k_hist2(const int* __restrict__ d0, int* __restrict__ c0,
                        const int* __restrict__ d1, int* __restrict__ c1) {
  int b = blockIdx.x;
  if (b < 1250) atomicAdd(&c0[d0[b * 256 + threadIdx.x]], 1);
  else atomicAdd(&c1[d1[(b - 1250) * 256 + threadIdx.x]], 1);
}

__global__ void k_scan2(const int* __restrict__ cnt0, int* __restrict__ off0, int* __restrict__ cur0,
                        const int* __restrict__ cnt1, int* __restrict__ off1, int* __restrict__ cur1,
                        int n) {
  const int* cnt = blockIdx.x ? cnt1 : cnt0;
  int* off = blockIdx.x ? off1 : off0;
  int* cur = blockIdx.x ? cur1 : cur0;
  __shared__ int warpsum[16];
  __shared__ int carry;
  int t = threadIdx.x;
  if (t == 0) carry = 0;
  __syncthreads();
  for (int base = 0; base < n; base += 1024) {
    int i = base + t;
    int v = (i < n) ? cnt[i] : 0;
    int lane = t & 63, w = t >> 6;
    int incl = v;
#pragma unroll
    for (int o = 1; o < 64; o <<= 1) {
      int u = __shfl_up(incl, o);
      if (lane >= o) incl += u;
    }
    if (lane == 63) warpsum[w] = incl;
    __syncthreads();
    if (t == 0) {
      int s = 0;
      for (int k = 0; k < 16; k++) { int x = warpsum[k]; warpsum[k] = s; s += x; }
    }
    __syncthreads();
    int excl = incl - v + warpsum[w] + carry;
    if (i < n) { off[i] = excl; cur[i] = excl; }
    __syncthreads();
    if (t == 1023) carry = excl + v;
    __syncthreads();
  }
  if (t == 0) off[n] = carry;
}

__global__ void k_scatter2(const int* __restrict__ d0, const int* __restrict__ s0,
                           int* __restrict__ cur0, int2* __restrict__ p0,
                           const int* __restrict__ d1, const int* __restrict__ s1,
                           int* __restrict__ cur1, int2* __restrict__ p1) {
  int b = blockIdx.x;
  if (b < 1250) {
    int e = b * 256 + threadIdx.x;
    int p = atomicAdd(&cur0[d0[e]], 1);
    p0[p] = make_int2(e, s0[e]);
  } else {
    int e = (b - 1250) * 256 + threadIdx.x;
    int p = atomicAdd(&cur1[d1[e]], 1);
    p1[p] = make_int2(e, s1[e]);
  }
}

// ---- aggregation: one WAVE per destination node, both graphs in one launch ----
// Sources are pre-weighted bf16 rows (512B gather/edge instead of 1KB fp32);
// attention already folded in; xe stream uses nontemporal loads to spare LLC.
__global__ __launch_bounds__(256) void k_agg(
    const unsigned short* __restrict__ xw_v, const unsigned short* __restrict__ xw_u,
    const float* __restrict__ xe_v2u, const float* __restrict__ xe_u2v,
    const int* __restrict__ off_u, const int* __restrict__ off_v,
    const int2* __restrict__ perm_u, const int2* __restrict__ perm_v,
    unsigned short* __restrict__ h_u, unsigned short* __restrict__ h_v) {
  int wid = (blockIdx.x * 256 + threadIdx.x) >> 6;
  int lane = threadIdx.x & 63;
  bool isU = wid < N_U;
  int node = isU ? wid : wid - N_U;
  const ushort4* xw4 = reinterpret_cast<const ushort4*>(isU ? xw_v : xw_u);
  const float* xe = isU ? xe_v2u : xe_u2v;
  const int* off = isU ? off_u : off_v;
  const int2* perm = isU ? perm_u : perm_v;
  unsigned short* h = isU ? h_u : h_v;

  int beg = off[node], end = off[node + 1];
  float4 s = {0.f, 0.f, 0.f, 0.f};
  float4 m4 = {NEG_HUGE, NEG_HUGE, NEG_HUGE, NEG_HUGE};
  float se = 0.f, me = NEG_HUGE;

  for (int c = beg; c < end; c += 64) {
    int n = end - c;
    n = n > 64 ? 64 : n;
    int2 pe = perm[c + (lane < n ? lane : 0)];
    int j = 0;
    for (; j + 4 <= n; j += 4) {
      int ey0 = __shfl(pe.y, j + 0), ex0 = __shfl(pe.x, j + 0);
      int ey1 = __shfl(pe.y, j + 1), ex1 = __shfl(pe.x, j + 1);
      int ey2 = __shfl(pe.y, j + 2), ex2 = __shfl(pe.x, j + 2);
      int ey3 = __shfl(pe.y, j + 3), ex3 = __shfl(pe.x, j + 3);
      ushort4 u0 = xw4[(size_t)ey0 * 64 + lane];
      ushort4 u1 = xw4[(size_t)ey1 * 64 + lane];
      ushort4 u2 = xw4[(size_t)ey2 * 64 + lane];
      ushort4 u3 = xw4[(size_t)ey3 * 64 + lane];
      float e0 = __builtin_nontemporal_load(xe + (size_t)ex0 * 64 + lane);
      float e1 = __builtin_nontemporal_load(xe + (size_t)ex1 * 64 + lane);
      float e2 = __builtin_nontemporal_load(xe + (size_t)ex2 * 64 + lane);
      float e3 = __builtin_nontemporal_load(xe + (size_t)ex3 * 64 + lane);
      float w0x = b2f(u0.x), w0y = b2f(u0.y), w0z = b2f(u0.z), w0w = b2f(u0.w);
      float w1x = b2f(u1.x), w1y = b2f(u1.y), w1z = b2f(u1.z), w1w = b2f(u1.w);
      float w2x = b2f(u2.x), w2y = b2f(u2.y), w2z = b2f(u2.z), w2w = b2f(u2.w);
      float w3x = b2f(u3.x), w3y = b2f(u3.y), w3z = b2f(u3.z), w3w = b2f(u3.w);
      s.x += w0x + w1x + w2x + w3x;
      s.y += w0y + w1y + w2y + w3y;
      s.z += w0z + w1z + w2z + w3z;
      s.w += w0w + w1w + w2w + w3w;
      m4.x = fmaxf(fmaxf(fmaxf(m4.x, w0x), fmaxf(w1x, w2x)), w3x);
      m4.y = fmaxf(fmaxf(fmaxf(m4.y, w0y), fmaxf(w1y, w2y)), w3y);
      m4.z = fmaxf(fmaxf(fmaxf(m4.z, w0z), fmaxf(w1z, w2z)), w3z);
      m4.w = fmaxf(fmaxf(fmaxf(m4.w, w0w), fmaxf(w1w, w2w)), w3w);
      se += e0 + e1 + e2 + e3;
      me = fmaxf(fmaxf(fmaxf(me, e0), fmaxf(e1, e2)), e3);
    }
    for (; j < n; j++) {
      int ey = __shfl(pe.y, j), ex = __shfl(pe.x, j);
      ushort4 u0 = xw4[(size_t)ey * 64 + lane];
      float ev = __builtin_nontemporal_load(xe + (size_t)ex * 64 + lane);
      float wx = b2f(u0.x), wy = b2f(u0.y), wz = b2f(u0.z), ww = b2f(u0.w);
      s.x += wx; s.y += wy; s.z += wz; s.w += ww;
      m4.x = fmaxf(m4.x, wx); m4.y = fmaxf(m4.y, wy);
      m4.z = fmaxf(m4.z, wz); m4.w = fmaxf(m4.w, ww);
      se += ev; me = fmaxf(me, ev);
    }
  }

  int deg = end - beg;
  float inv = 1.f / (float)(deg > 0 ? deg : 1);
  size_t hb = (size_t)node * 896;
  ushort4* h4 = reinterpret_cast<ushort4*>(h + hb);
  h4[64 + lane] = bf4(make_float4(s.x * inv, s.y * inv, s.z * inv, s.w * inv));
  float4 mo = deg > 0 ? m4 : make_float4(0.f, 0.f, 0.f, 0.f);
  h4[128 + lane] = bf4(mo);
  h[hb + 768 + lane] = f2bf(se * inv);
  h[hb + 832 + lane] = f2bf(deg > 0 ? me : 0.f);
}

// ---- LDS-tiled weight transpose (fp32 [K][N] -> bf16 [N][K]), coalesced both ways ----
// tiles: W0/W1: 14x4 = 56 each; W2: 9x1 = 9. grid = 121 blocks.
__global__ void k_wt_tiled(const float* __restrict__ W0, const float* __restrict__ W1,
                           const float* __restrict__ W2, unsigned short* __restrict__ T0,
                           unsigned short* __restrict__ T1, unsigned short* __restrict__ T2) {
  __shared__ unsigned short tile[64][66];  // 132B row stride = 33 banks (odd) -> conflict-free
  int b = blockIdx.x;
  const float* W;
  unsigned short* T;
  int K, N;
  if (b < 56) { W = W0; T = T0; K = 896; N = 256; }
  else if (b < 112) { b -= 56; W = W1; T = T1; K = 896; N = 256; }
  else { b -= 112; W = W2; T = T2; K = 576; N = 64; }
  int ntn = N >> 6;
  int k0 = (b / ntn) << 6, n0 = (b % ntn) << 6;
  int t = threadIdx.x;
#pragma unroll
  for (int i = 0; i < 16; i++) {
    int idx = t + i * 256;
    int k = idx >> 6, n = idx & 63;
    tile[k][n] = f2bf(W[(size_t)(k0 + k) * N + n0 + n]);
  }
  __syncthreads();
#pragma unroll
  for (int i = 0; i < 16; i++) {
    int idx = t + i * 256;
    int n = idx >> 6, k = idx & 63;
    T[(size_t)(n0 + n) * K + k0 + k] = tile[k][n];
  }
}

// ---- bf16 MFMA GEMM, z selects among 2 problem instances; optional fused col-stats ----
template <int TN, bool STATS>
__global__ __launch_bounds__(256) void k_gemm(
    const unsigned short* __restrict__ A0, const unsigned short* __restrict__ A1, int lda,
    const unsigned short* __restrict__ B0, const unsigned short* __restrict__ B1, int ldb,
    float* __restrict__ C0, float* __restrict__ C1, int ldc, int M, int K,
    float* __restrict__ sum0, float* __restrict__ sum1,
    float* __restrict__ sq0, float* __restrict__ sq1) {
  constexpr int WAVES_N = TN / 64;
  constexpr int WAVES_M = 4 / WAVES_N;
  constexpr int WTM = 128 / WAVES_M;
  constexpr int MT = WTM / 16;
  constexpr int NT = 4;
  constexpr int LS = 56;  // padded k-stride (ushorts): 112B rows, 16B-aligned, ~2-way banks

  __shared__ __align__(16) unsigned short As[128 * LS];
  __shared__ __align__(16) unsigned short Bs[TN * LS];
  __shared__ float ssum[TN], ssq[TN];

  const unsigned short* A = blockIdx.z ? A1 : A0;
  const unsigned short* B = blockIdx.z ? B1 : B0;
  float* C = blockIdx.z ? C1 : C0;
  float* sum = blockIdx.z ? sum1 : sum0;
  float* sq = blockIdx.z ? sq1 : sq0;

  const int t = threadIdx.x;
  const int m0 = blockIdx.x * 128;
  const int n0 = blockIdx.y * TN;
  const int lane = t & 63;
  const int w = t >> 6;
  const int wm = w % WAVES_M;
  const int wn = w / WAVES_M;

  if (STATS && t < TN) { ssum[t] = 0.f; ssq[t] = 0.f; }

  f32x4 acc[MT][NT];
#pragma unroll
  for (int i = 0; i < MT; i++)
#pragma unroll
    for (int j = 0; j < NT; j++) acc[i][j] = (f32x4){0.f, 0.f, 0.f, 0.f};

  const int arow_l = wm * WTM + (lane & 15);
  const int koff_l = (lane >> 4) * 8;

  for (int k0 = 0; k0 < K; k0 += 32) {
    if (k0) __syncthreads();
#pragma unroll
    for (int p = 0; p < 2; p++) {
      int c = t + p * 256;
      int row = c >> 2, kc = c & 3;
      int rg = m0 + row;
      rg = rg < M ? rg : M - 1;
      *reinterpret_cast<uint4*>(&As[row * LS + kc * 8]) =
          *reinterpret_cast<const uint4*>(A + (size_t)rg * lda + k0 + kc * 8);
    }
#pragma unroll
    for (int p = 0; p < TN / 64; p++) {
      int c = t + p * 256;
      int row = c >> 2, kc = c & 3;
      *reinterpret_cast<uint4*>(&Bs[row * LS + kc * 8]) =
          *reinterpret_cast<const uint4*>(B + (size_t)(n0 + row) * ldb + k0 + kc * 8);
    }
    __syncthreads();
    bf16x8 af[MT], bfv[NT];
#pragma unroll
    for (int i = 0; i < MT; i++)
      af[i] = *reinterpret_cast<const bf16x8*>(&As[(arow_l + i * 16) * LS + koff_l]);
#pragma unroll
    for (int j = 0; j < NT; j++)
      bfv[j] = *reinterpret_cast<const bf16x8*>(&Bs[(wn * 64 + j * 16 + (lane & 15)) * LS + koff_l]);
#pragma unroll
    for (int i = 0; i < MT; i++)
#pragma unroll
      for (int j = 0; j < NT; j++)
        acc[i][j] = __builtin_amdgcn_mfma_f32_16x16x32_bf16(af[i], bfv[j], acc[i][j], 0, 0, 0);
  }

  float st[NT], qt[NT];
#pragma unroll
  for (int j = 0; j < NT; j++) { st[j] = 0.f; qt[j] = 0.f; }
#pragma unroll
  for (int i = 0; i < MT; i++) {
#pragma unroll
    for (int j = 0; j < NT; j++) {
      int col = n0 + wn * 64 + j * 16 + (lane & 15);
#pragma unroll
      for (int r = 0; r < 4; r++) {
        int row = m0 + wm * WTM + i * 16 + (lane >> 4) * 4 + r;
        if (row < M) {
          float v = acc[i][j][r];
          C[(size_t)row * ldc + col] = v;
          if (STATS) { st[j] += v; qt[j] += v * v; }
        }
      }
    }
  }
  if (STATS) {
#pragma unroll
    for (int j = 0; j < NT; j++) {
      st[j] += __shfl_xor(st[j], 16); st[j] += __shfl_xor(st[j], 32);
      qt[j] += __shfl_xor(qt[j], 16); qt[j] += __shfl_xor(qt[j], 32);
    }
    if (lane < 16) {
#pragma unroll
      for (int j = 0; j < NT; j++) {
        atomicAdd(&ssum[wn * 64 + j * 16 + lane], st[j]);
        atomicAdd(&ssq[wn * 64 + j * 16 + lane], qt[j]);
      }
    }
    __syncthreads();
    if (t < TN) {
      atomicAdd(&sum[n0 + t], ssum[t]);
      atomicAdd(&sq[n0 + t], ssq[t]);
    }
  }
}

// ---- fused edge GEMM: pe = bf16(xe_e) @ W1, += pu[row_e] + pv[col_e], col-stats ----
__global__ __launch_bounds__(256) void k_gemm_e(
    const float* __restrict__ xe_e, const unsigned short* __restrict__ Wt,  // [64][576], k<64
    const int* __restrict__ rowe, const int* __restrict__ cole,
    const float* __restrict__ pu, const float* __restrict__ pv,
    float* __restrict__ OutE, float* __restrict__ sum, float* __restrict__ sq) {
  constexpr int LSB = 72;  // padded k-stride: 144B rows
  __shared__ __align__(16) unsigned short Bs[64 * LSB];
  __shared__ float ssum[64], ssq[64];
  int t = threadIdx.x;
  int lane = t & 63, w = t >> 6;
  if (t < 64) { ssum[t] = 0.f; ssq[t] = 0.f; }
  {
    int row = t >> 2, seg = t & 3;
    const uint4* src = reinterpret_cast<const uint4*>(Wt + (size_t)row * 576 + seg * 16);
    uint4* dst = reinterpret_cast<uint4*>(&Bs[row * LSB + seg * 16]);
    dst[0] = src[0];
    dst[1] = src[1];
  }
  __syncthreads();

  int m0 = blockIdx.x * 128;
  f32x4 acc[2][4];
#pragma unroll
  for (int i = 0; i < 2; i++)
#pragma unroll
    for (int j = 0; j < 4; j++) acc[i][j] = (f32x4){0.f, 0.f, 0.f, 0.f};

#pragma unroll
  for (int k0 = 0; k0 < 64; k0 += 32) {
    bf16x8 af[2], bfv[4];
#pragma unroll
    for (int i = 0; i < 2; i++) {
      int row = m0 + w * 32 + i * 16 + (lane & 15);
      const float4* ap = reinterpret_cast<const float4*>(xe_e + (size_t)row * 64 + k0 + (lane >> 4) * 8);
      float4 a0 = ap[0], a1 = ap[1];
      union { bf16x8 v; ushort4 u[2]; } pk;
      pk.u[0] = bf4(a0);
      pk.u[1] = bf4(a1);
      af[i] = pk.v;
    }
#pragma unroll
    for (int j = 0; j < 4; j++)
      bfv[j] = *reinterpret_cast<const bf16x8*>(&Bs[(j * 16 + (lane & 15)) * LSB + k0 + (lane >> 4) * 8]);
#pragma unroll
    for (int i = 0; i < 2; i++)
#pragma unroll
      for (int j = 0; j < 4; j++)
        acc[i][j] = __builtin_amdgcn_mfma_f32_16x16x32_bf16(af[i], bfv[j], acc[i][j], 0, 0, 0);
  }

  float st[4] = {0.f, 0.f, 0.f, 0.f}, qt[4] = {0.f, 0.f, 0.f, 0.f};
#pragma unroll
  for (int i = 0; i < 2; i++) {
    int base = m0 + w * 32 + i * 16 + (lane >> 4) * 4;
#pragma unroll
    for (int r = 0; r < 4; r++) {
      int e = base + r;
      int ru = rowe[e], cv = cole[e];
      const float* pur = pu + (size_t)ru * 64;
      const float* pvr = pv + (size_t)cv * 64;
#pragma unroll
      for (int j = 0; j < 4; j++) {
        int col = j * 16 + (lane & 15);
        float v = acc[i][j][r] + pur[col] + pvr[col];
        OutE[(size_t)e * 64 + col] = v;
        st[j] += v;
        qt[j] += v * v;
      }
    }
  }
#pragma unroll
  for (int j = 0; j < 4; j++) {
    st[j] += __shfl_xor(st[j], 16); st[j] += __shfl_xor(st[j], 32);
    qt[j] += __shfl_xor(qt[j], 16); qt[j] += __shfl_xor(qt[j], 32);
  }
  if (lane < 16) {
#pragma unroll
    for (int j = 0; j < 4; j++) {
      atomicAdd(&ssum[j * 16 + lane], st[j]);
      atomicAdd(&ssq[j * 16 + lane], qt[j]);
    }
  }
  __syncthreads();
  if (t < 64) {
    atomicAdd(&sum[t], ssum[t]);
    atomicAdd(&sq[t], ssq[t]);
  }
}

// ---- BN apply, all three outputs, float4 per thread ----
__global__ void k_bn4(float* __restrict__ out_u, float* __restrict__ out_v,
                      float* __restrict__ out_e, const float* __restrict__ stats,
                      const float* __restrict__ g_u, const float* __restrict__ be_u,
                      const float* __restrict__ g_v, const float* __restrict__ be_v,
                      const float* __restrict__ g_e, const float* __restrict__ be_e) {
  int b = blockIdx.x;
  float* X;
  const float *sum, *sq, *g, *be;
  int cmask;
  float invn;
  long base;
  if (b < 5000) {
    X = out_u; base = (long)b * 1024; sum = stats; sq = stats + 256;
    g = g_u; be = be_u; cmask = 255; invn = 1.f / N_U;
  } else if (b < 10000) {
    X = out_v; base = (long)(b - 5000) * 1024; sum = stats + 512; sq = stats + 768;
    g = g_v; be = be_v; cmask = 255; invn = 1.f / N_V;
  } else {
    X = out_e; base = (long)(b - 10000) * 1024; sum = stats + 1024; sq = stats + 1088;
    g = g_e; be = be_e; cmask = 63; invn = 1.f / N_E;
  }
  long i4 = base + (long)threadIdx.x * 4;
  int c0 = (int)(i4 & cmask);
  float4 v = *reinterpret_cast<float4*>(X + i4);
  float r[4] = {v.x, v.y, v.z, v.w};
#pragma unroll
  for (int k = 0; k < 4; k++) {
    int c = c0 + k;
    float mu = sum[c] * invn;
    float var = sq[c] * invn - mu * mu;
    r[k] = (r[k] - mu) * rsqrtf(var + EPS_F) * g[c] + be[c];
  }
  *reinterpret_cast<float4*>(X + i4) = make_float4(r[0], r[1], r[2], r[3]);
}

extern "C" void kernel_launch(void* const* d_in, const int* in_sizes, int n_in, void* d_out,
                              int out_size, void* d_ws, size_t ws_size, hipStream_t stream) {
  (void)in_sizes; (void)n_in; (void)out_size; (void)ws_size;
  const float* xus = (const float*)d_in[0];
  const float* xut = (const float*)d_in[1];
  const float* xvs = (const float*)d_in[2];
  const float* xvt = (const float*)d_in[3];
  const float* xe_e = (const float*)d_in[4];
  const float* xe_v2u = (const float*)d_in[5];
  const float* xe_u2v = (const float*)d_in[6];
  const int* row_v2u = (const int*)d_in[7];
  const int* col_v2u = (const int*)d_in[8];
  const int* row_u2v = (const int*)d_in[9];
  const int* col_u2v = (const int*)d_in[10];
  const int* row_e = (const int*)d_in[11];
  const int* col_e = (const int*)d_in[12];
  const float* W_v2u = (const float*)d_in[14];
  const float* g_v2u = (const float*)d_in[16];
  const float* be_v2u = (const float*)d_in[17];
  const float* W_u2v = (const float*)d_in[19];
  const float* g_u2v = (const float*)d_in[21];
  const float* be_u2v = (const float*)d_in[22];
  const float* W_e = (const float*)d_in[23];
  const float* g_e = (const float*)d_in[25];
  const float* be_e = (const float*)d_in[26];
  const float* attn_v2u = (const float*)d_in[13];
  const float* attn_u2v = (const float*)d_in[18];

  char* p = (char*)d_ws;
  auto alloc = [&](size_t bytes) {
    char* r = p;
    p += (bytes + 15) & ~(size_t)15;
    return r;
  };
  // zero zone (contiguous prefix)
  int* cnt_u = (int*)alloc(N_U * 4);
  int* cnt_v = (int*)alloc(N_V * 4);
  float* stats = (float*)alloc(1152 * 4);
  size_t zero_bytes = (size_t)(p - (char*)d_ws);
  // rest
  int* off_u = (int*)alloc((N_U + 1) * 4);
  int* cur_u = (int*)alloc(N_U * 4);
  int2* perm_u = (int2*)alloc((size_t)N_E * 8);
  int* off_v = (int*)alloc((N_V + 1) * 4);
  int* cur_v = (int*)alloc(N_V * 4);
  int2* perm_v = (int2*)alloc((size_t)N_E * 8);
  float* logits_u = (float*)alloc(N_U * 4);
  float* logits_v = (float*)alloc(N_V * 4);
  float* smstat = (float*)alloc(8 * 4);
  unsigned short* h_u = (unsigned short*)alloc((size_t)N_U * 896 * 2);
  unsigned short* h_v = (unsigned short*)alloc((size_t)N_V * 896 * 2);
  unsigned short* Wt_v2u = (unsigned short*)alloc((size_t)896 * 256 * 2);
  unsigned short* Wt_u2v = (unsigned short*)alloc((size_t)896 * 256 * 2);
  unsigned short* Wt_e = (unsigned short*)alloc((size_t)576 * 64 * 2);
  float* pu = (float*)alloc((size_t)N_U * 64 * 4);
  float* pv = (float*)alloc((size_t)N_V * 64 * 4);
  unsigned short* xw_u = (unsigned short*)alloc((size_t)N_U * 256 * 2);
  unsigned short* xw_v = (unsigned short*)alloc((size_t)N_V * 256 * 2);

  float* out_u = (float*)d_out;
  float* out_v = out_u + (size_t)N_U * 256;
  float* out_e = out_v + (size_t)N_V * 256;

  hipMemsetAsync(d_ws, 0, zero_bytes, stream);

  k_logits2<<<10000, 256, 0, stream>>>(xus, xvs, attn_u2v, attn_v2u, logits_u, logits_v);
  k_softmax_stat<<<2, 1024, 0, stream>>>(logits_u, logits_v, smstat, N_U);
  k_preweight<<<10000, 256, 0, stream>>>(xus, xvs, xut, xvt, logits_u, logits_v, smstat,
                                         xw_u, xw_v, h_u, h_v);
  k_hist2<<<2500, 256, 0, stream>>>(row_v2u, cnt_u, col_u2v, cnt_v);
  k_scan2<<<2, 1024, 0, stream>>>(cnt_u, off_u, cur_u, cnt_v, off_v, cur_v, N_U);
  k_scatter2<<<2500, 256, 0, stream>>>(row_v2u, col_v2u, cur_u, perm_u, col_u2v, row_u2v, cur_v, perm_v);
  k_agg<<<10000, 256, 0, stream>>>(xw_v, xw_u, xe_v2u, xe_u2v,
                                   off_u, off_v, perm_u, perm_v, h_u, h_v);
  k_wt_tiled<<<121, 256, 0, stream>>>(W_v2u, W_u2v, W_e, Wt_v2u, Wt_u2v, Wt_e);

  // node GEMMs with fused BN col-stats (z: 0=u, 1=v)
  k_gemm<128, true><<<dim3(157, 2, 2), 256, 0, stream>>>(
      h_u, h_v, 896, Wt_v2u, Wt_u2v, 896, out_u, out_v, 256, N_U, 896,
      stats, stats + 512, stats + 256, stats + 768);
  // pu/pv GEMMs (z: 0=pu from h_u cols0..255, 1=pv)
  k_gemm<64, false><<<dim3(157, 1, 2), 256, 0, stream>>>(
      h_u, h_v, 896, Wt_e + 64, Wt_e + 320, 576, pu, pv, 64, N_U, 256,
      nullptr, nullptr, nullptr, nullptr);
  // fused edge GEMM + assemble + stats
  k_gemm_e<<<2500, 256, 0, stream>>>(xe_e, Wt_e, row_e, col_e, pu, pv, out_e,
                                     stats + 1024, stats + 1088);
  k_bn4<<<30000, 256, 0, stream>>>(out_u, out_v, out_e, stats, g_v2u, be_v2u,
                                   g_u2v, be_u2v, g_e, be_e);
}